// Round 1
// baseline (427.983 us; speedup 1.0000x reference)
//
#include <hip/hip_runtime.h>
#include <hip/hip_bf16.h>
#include <cstdint>
#include <cstddef>

#define N 4096
#define NN ((size_t)N * (size_t)N)

typedef int   int4v   __attribute__((ext_vector_type(4)));
typedef float float4v __attribute__((ext_vector_type(4)));

__device__ inline void async16(const void* g, void* lds) {
    __builtin_amdgcn_global_load_lds(
        (const __attribute__((address_space(1))) void*)g,
        (__attribute__((address_space(3))) void*)lds, 16, 0, 0);
}

// ---------------- kernel 1: straight-through relaxed Bernoulli flip ----------------
// float4-vectorized; per-element math is op-for-op identical to the proven scalar
// version (bit-exact, absmax must stay 0).
__global__ void mod_kernel(const float* __restrict__ ori,
                           const float* __restrict__ clp,
                           const float* __restrict__ u,
                           float* __restrict__ out) {
    size_t i = ((size_t)blockIdx.x * blockDim.x + threadIdx.x) * 4;
    const float4v p4 = *(const float4v*)(clp + i);
    const float4v u4 = *(const float4v*)(u + i);
    const float4v o4 = *(const float4v*)(ori + i);
    float4v r;
    #pragma unroll
    for (int c = 0; c < 4; ++c) {
        float p = fminf(fmaxf(p4[c], 1e-10f), 1.0f - 1e-10f);
        float logits = logf(p) - log1pf(-p);
        float uu = u4[c];
        float noise = logf(uu) - log1pf(-uu);
        float y = (logits + noise) / 0.2f;
        float soft = 1.0f / (1.0f + expf(-y));
        float hard = rintf(soft);
        float o = o4[c];
        r[c] = o + hard * (-2.0f * o);
    }
    *(float4v*)(out + i) = r;
}

// ---------------- kernel 2: diagonal extract + zero accumulators ----------------
__global__ void diag_kernel(const float* __restrict__ mod,
                            float* __restrict__ diag,
                            double* __restrict__ accs) {
    int j = blockIdx.x * blockDim.x + threadIdx.x;
    if (j < N) diag[j] = mod[(size_t)j * N + j];
    if (blockIdx.x == 0 && threadIdx.x < 2) accs[threadIdx.x] = 0.0;
}

// ---------------- kernel 3: A = mod + mod^T - diag(col) as i8: A, AT, |A|, |A|T ----------------
__global__ void build_A8(const float* __restrict__ mod,
                         const float* __restrict__ diag,
                         signed char* __restrict__ A,
                         signed char* __restrict__ AT,
                         signed char* __restrict__ Aa,
                         signed char* __restrict__ ATa) {
    __shared__ float tji[32][33];        // tji[j-local][i-local] = mod[j][i]
    __shared__ signed char cv[32][36];   // cv[i-local][j-local] = A value
    const int bi = blockIdx.x * 32;
    const int bj = blockIdx.y * 32;
    const int tx = threadIdx.x;   // 0..7  (groups of 4 cols)
    const int ty = threadIdx.y;   // 0..31 (rows)
    {
        const float4 v = *(const float4*)&mod[(size_t)(bj + ty) * N + bi + tx * 4];
        tji[ty][tx * 4 + 0] = v.x; tji[ty][tx * 4 + 1] = v.y;
        tji[ty][tx * 4 + 2] = v.z; tji[ty][tx * 4 + 3] = v.w;
    }
    __syncthreads();
    const float4 mv = *(const float4*)&mod[(size_t)(bi + ty) * N + bj + tx * 4];
    float m4[4] = {mv.x, mv.y, mv.z, mv.w};
    int pkA = 0, pkAa = 0;
    #pragma unroll
    for (int k = 0; k < 4; ++k) {
        int jl = tx * 4 + k;
        float a = m4[k] + tji[jl][ty] - diag[bj + jl];  // exact small integer
        int ai = (int)a;
        cv[ty][jl] = (signed char)ai;
        int au = ai < 0 ? -ai : ai;
        pkA  |= (ai & 255) << (8 * k);
        pkAa |= (au & 255) << (8 * k);
    }
    *(int*)&A [(size_t)(bi + ty) * N + bj + tx * 4] = pkA;
    *(int*)&Aa[(size_t)(bi + ty) * N + bj + tx * 4] = pkAa;
    __syncthreads();
    int pkT = 0, pkTa = 0;
    #pragma unroll
    for (int k = 0; k < 4; ++k) {
        int il = tx * 4 + k;
        int v = cv[il][ty];                 // A[i-local=il][j-local=ty] -> AT[j][i]
        int va = v < 0 ? -v : v;
        pkT  |= (v  & 255) << (8 * k);
        pkTa |= (va & 255) << (8 * k);
    }
    *(int*)&AT [(size_t)(bj + ty) * N + bi + tx * 4] = pkT;
    *(int*)&ATa[(size_t)(bj + ty) * N + bi + tx * 4] = pkTa;
}

// ---------------- kernel 4: i8 GEMM-trace, 256x256 tile, 4-deep pipelined schedule -------
// acc[z] = sum_{i,k} (M.M)[i,k] * M[k,i], M = A (z=0) or |A| (z=1). Exact integer math.
//
// Schedule (T3+T4+T5 port of the 8-phase template):
//   4 LDS buffers (tile j uses buffer j&3), lookahead-3 prefetch via global_load_lds.
//   Per K-tile (BK=64): 2 phases x {8/4 ds_read_b128; 2 async loads(j+3); s_barrier;
//   lgkmcnt(0)+sched_barrier; setprio(1); 16 MFMA; setprio(0); [vmcnt(8) end of tile];
//   s_barrier}.  Steady-state vmcnt(8) = 12 in flight, wait only the oldest tile —
//   never drains to 0 in the main loop.  Raw s_barrier (no compiler vmcnt(0) drain).
//   Hazards: lookahead 3 < 4 buffers => staging never targets a buffer that is being
//   read this tile or the next two; the end-of-tile vmcnt+barrier makes buffer j+1
//   ready for tile j+1's phase-A ds_reads across all waves.
#define BK 64
#define NT (N / BK)      // 64 K-tiles
#define BUFSZ 32768      // A 16K + B 16K per buffer

__global__ __launch_bounds__(512, 2) void gemm_trace_i8(
        const signed char* __restrict__ Ag,
        const signed char* __restrict__ ATg,
        const signed char* __restrict__ Aag,
        const signed char* __restrict__ ATag,
        double* __restrict__ accs) {
    __shared__ __align__(16) signed char lds[4 * BUFSZ];   // 128 KiB
    __shared__ int red[8];
    const int z = blockIdx.z;
    const signed char* Asrc = z ? Aag  : Ag;    // M rows   (i-panel)
    const signed char* Bsrc = z ? ATag : ATg;   // MT rows  (k-panel), B[k][n] = MT[n][k]
    const int i0 = blockIdx.y * 256;
    const int k0 = blockIdx.x * 256;
    const int t = threadIdx.x;
    const int lane = t & 63;
    const int wave = t >> 6;        // 0..7
    const int wm = wave >> 2;       // 0..1 -> M offset wm*128
    const int wn = wave & 3;        // 0..3 -> N offset wn*64
    const int quad = lane >> 4;
    const int col  = lane & 15;

    // staging plan: A tile = 1024 chunks of 16B (256 rows x 4 slots); thread t owns
    // chunks t and t+512 of A, same of B.  LDS slot c holds global slot (c&3)^((r>>1)&3)
    // (involution; pre-swizzled global source, linear LDS dest — required by
    // global_load_lds).
    const int c1 = t;
    const int r1 = c1 >> 2;          // 0..127
    const int r2 = r1 + 128;
    const int s1 = (((c1 & 3) ^ ((r1 >> 1) & 3)) << 4);
    const int s2 = (((c1 & 3) ^ ((r2 >> 1) & 3)) << 4);
    const signed char* gA1 = Asrc + (size_t)(i0 + r1) * N + s1;
    const signed char* gA2 = Asrc + (size_t)(i0 + r2) * N + s2;
    const signed char* gB1 = Bsrc + (size_t)(k0 + r1) * N + s1;
    const signed char* gB2 = Bsrc + (size_t)(k0 + r2) * N + s2;
    const int ldsA1 = (wave * 64) * 16;           // wave-uniform LDS bases
    const int ldsA2 = 8192  + (wave * 64) * 16;
    const int ldsB1 = 16384 + (wave * 64) * 16;
    const int ldsB2 = 24576 + (wave * 64) * 16;
    const int fsw = ((quad ^ ((col >> 1) & 3)) << 4);  // fragment k-slot after swizzle

    int4v acc[8][4];
    #pragma unroll
    for (int a = 0; a < 8; ++a)
        #pragma unroll
        for (int b = 0; b < 4; ++b)
            acc[a][b] = (int4v){0, 0, 0, 0};

    // prologue: stage tiles 0,1,2 (12 loads in flight), wait tile 0 only
    for (int p = 0; p < 3; ++p) {
        const int pb = p * BUFSZ;
        const size_t go = (size_t)p * BK;
        async16(gA1 + go, lds + pb + ldsA1);
        async16(gA2 + go, lds + pb + ldsA2);
        async16(gB1 + go, lds + pb + ldsB1);
        async16(gB2 + go, lds + pb + ldsB2);
    }
    asm volatile("s_waitcnt vmcnt(8)" ::: "memory");
    __builtin_amdgcn_s_barrier();

    int4v bf[4];
    for (int j = 0; j < NT; ++j) {
        const int buf = (j & 3) * BUFSZ;
        const signed char* Ab = lds + buf;
        const signed char* Bb = lds + buf + 16384;
        const int pre = j + 3;
        const size_t go = (size_t)pre * BK;
        const int pb = (pre & 3) * BUFSZ;
        int4v af[4];
        // ---- phase A: m-half 0 ----
        #pragma unroll
        for (int tr = 0; tr < 4; ++tr)
            af[tr] = *(const int4v*)(Ab + ((wm * 128 + tr * 16 + col) << 6) + fsw);
        #pragma unroll
        for (int tc = 0; tc < 4; ++tc)
            bf[tc] = *(const int4v*)(Bb + ((wn * 64 + tc * 16 + col) << 6) + fsw);
        if (pre < NT) {
            async16(gA1 + go, lds + pb + ldsA1);
            async16(gA2 + go, lds + pb + ldsA2);
        }
        __builtin_amdgcn_s_barrier();
        asm volatile("s_waitcnt lgkmcnt(0)" ::: "memory");
        __builtin_amdgcn_sched_barrier(0);
        __builtin_amdgcn_s_setprio(1);
        #pragma unroll
        for (int tr = 0; tr < 4; ++tr)
            #pragma unroll
            for (int tc = 0; tc < 4; ++tc)
                acc[tr][tc] = __builtin_amdgcn_mfma_i32_16x16x64_i8(af[tr], bf[tc], acc[tr][tc], 0, 0, 0);
        __builtin_amdgcn_s_setprio(0);
        __builtin_amdgcn_s_barrier();
        // ---- phase B: m-half 1 (bf reused, k fixed per tile) ----
        #pragma unroll
        for (int tr = 0; tr < 4; ++tr)
            af[tr] = *(const int4v*)(Ab + ((wm * 128 + 64 + tr * 16 + col) << 6) + fsw);
        if (pre < NT) {
            async16(gB1 + go, lds + pb + ldsB1);
            async16(gB2 + go, lds + pb + ldsB2);
        }
        __builtin_amdgcn_s_barrier();
        asm volatile("s_waitcnt lgkmcnt(0)" ::: "memory");
        __builtin_amdgcn_sched_barrier(0);
        __builtin_amdgcn_s_setprio(1);
        #pragma unroll
        for (int tr = 0; tr < 4; ++tr)
            #pragma unroll
            for (int tc = 0; tc < 4; ++tc)
                acc[4 + tr][tc] = __builtin_amdgcn_mfma_i32_16x16x64_i8(af[tr], bf[tc], acc[4 + tr][tc], 0, 0, 0);
        __builtin_amdgcn_s_setprio(0);
        // end-of-tile counted wait: make buffer j+1 ready for next tile's phase-A reads
        if (j < NT - 3)       { asm volatile("s_waitcnt vmcnt(8)" ::: "memory"); }
        else if (j == NT - 3) { asm volatile("s_waitcnt vmcnt(4)" ::: "memory"); }
        else if (j == NT - 2) { asm volatile("s_waitcnt vmcnt(0)" ::: "memory"); }
        __builtin_amdgcn_s_barrier();
    }

    // trace epilogue: C/D layout col=lane&15, row=quad*4+reg (shape-determined).
    // multiplier M[k,i] = Asrc[kk*N + ib + r]: 4 consecutive bytes -> one int load.
    int part = 0;
    #pragma unroll
    for (int mr = 0; mr < 8; ++mr) {
        const int ib = i0 + wm * 128 + mr * 16 + quad * 4;
        #pragma unroll
        for (int tc = 0; tc < 4; ++tc) {
            const int kk = k0 + wn * 64 + tc * 16 + col;
            const int mv = *(const int*)&Asrc[(size_t)kk * N + ib];
            #pragma unroll
            for (int r = 0; r < 4; ++r)
                part += acc[mr][tc][r] * (int)(signed char)(mv >> (8 * r));
        }
    }
    #pragma unroll
    for (int off = 32; off > 0; off >>= 1)
        part += __shfl_down(part, off, 64);
    if (lane == 0) red[wave] = part;
    __syncthreads();
    if (t == 0) {
        int tot = 0;
        #pragma unroll
        for (int w = 0; w < 8; ++w) tot += red[w];
        atomicAdd(&accs[z], (double)tot);
    }
}

// ---------------- kernel 5: balance ----------------
__global__ void finalize_kernel(const double* __restrict__ accs, float* __restrict__ out) {
    out[NN] = (float)(0.5 * (1.0 + accs[0] / accs[1]));
}

extern "C" void kernel_launch(void* const* d_in, const int* in_sizes, int n_in,
                              void* d_out, int out_size, void* d_ws, size_t ws_size,
                              hipStream_t stream) {
    const float* ori = (const float*)d_in[0];
    const float* clp = (const float*)d_in[1];
    const float* u   = (const float*)d_in[2];
    float* out = (float*)d_out;
    char* ws = (char*)d_ws;
    signed char* A8   = (signed char*)ws;                    // 16 MiB
    signed char* AT8  = (signed char*)(ws + NN);             // 16 MiB
    signed char* Aa8  = (signed char*)(ws + 2 * NN);         // 16 MiB
    signed char* ATa8 = (signed char*)(ws + 3 * NN);         // 16 MiB
    float*       diag = (float*)(ws + 4 * NN);               // 16 KiB
    double*      accs = (double*)(ws + 4 * NN + 4096 * 4);   // 16 B

    mod_kernel<<<dim3((unsigned)(NN / 1024)), 256, 0, stream>>>(ori, clp, u, out);
    diag_kernel<<<dim3(16), 256, 0, stream>>>(out, diag, accs);
    build_A8<<<dim3(N / 32, N / 32), dim3(8, 32), 0, stream>>>(out, diag, A8, AT8, Aa8, ATa8);
    gemm_trace_i8<<<dim3(N / 256, N / 256, 2), 512, 0, stream>>>(A8, AT8, Aa8, ATa8, accs);
    finalize_kernel<<<1, 1, 0, stream>>>(accs, out);
}

// Round 2
// 378.132 us; speedup vs baseline: 1.1318x; 1.1318x over previous
//
#include <hip/hip_runtime.h>
#include <hip/hip_bf16.h>
#include <cstdint>
#include <cstddef>

#define N 4096
#define NN ((size_t)N * (size_t)N)

typedef int   int4v   __attribute__((ext_vector_type(4)));
typedef float float4v __attribute__((ext_vector_type(4)));

__device__ inline void async16(const void* g, void* lds) {
    __builtin_amdgcn_global_load_lds(
        (const __attribute__((address_space(1))) void*)g,
        (__attribute__((address_space(3))) void*)lds, 16, 0, 0);
}

// ---------------- kernel 1: straight-through relaxed Bernoulli flip ----------------
// Algebraic shortcut: hard = rint(sigmoid((logit(p)+logit(u))/tau)) == (p + u >= 1),
// since logit(p)+logit(u) >= 0  <=>  p*u >= (1-p)(1-u)  <=>  p+u >= 1  (tau>0 and
// sigmoid are monotone; p-clamp inactive at the boundary because u <= 1-1e-6).
// out = o + hard*(-2o), via fmaf to preserve +0.0 exactly.  Memory-bound.
__global__ void mod_kernel(const float* __restrict__ ori,
                           const float* __restrict__ clp,
                           const float* __restrict__ u,
                           float* __restrict__ out) {
    size_t i = ((size_t)blockIdx.x * blockDim.x + threadIdx.x) * 4;
    const float4v p4 = *(const float4v*)(clp + i);
    const float4v u4 = *(const float4v*)(u + i);
    const float4v o4 = *(const float4v*)(ori + i);
    float4v r;
    #pragma unroll
    for (int c = 0; c < 4; ++c) {
        float hard = (p4[c] + u4[c] >= 1.0f) ? 1.0f : 0.0f;
        r[c] = fmaf(hard, -2.0f * o4[c], o4[c]);
    }
    *(float4v*)(out + i) = r;
}

// ---------------- kernel 2: diagonal extract + zero accumulators ----------------
__global__ void diag_kernel(const float* __restrict__ mod,
                            float* __restrict__ diag,
                            double* __restrict__ accs) {
    int j = blockIdx.x * blockDim.x + threadIdx.x;
    if (j < N) diag[j] = mod[(size_t)j * N + j];
    if (blockIdx.x == 0 && threadIdx.x < 2) accs[threadIdx.x] = 0.0;
}

// ---------------- kernel 3: A = mod + mod^T - diag(col) as i8: A, AT, |A|, |A|T ----------------
__global__ void build_A8(const float* __restrict__ mod,
                         const float* __restrict__ diag,
                         signed char* __restrict__ A,
                         signed char* __restrict__ AT,
                         signed char* __restrict__ Aa,
                         signed char* __restrict__ ATa) {
    __shared__ float tji[32][33];        // tji[j-local][i-local] = mod[j][i]
    __shared__ signed char cv[32][36];   // cv[i-local][j-local] = A value
    const int bi = blockIdx.x * 32;
    const int bj = blockIdx.y * 32;
    const int tx = threadIdx.x;   // 0..7  (groups of 4 cols)
    const int ty = threadIdx.y;   // 0..31 (rows)
    {
        const float4 v = *(const float4*)&mod[(size_t)(bj + ty) * N + bi + tx * 4];
        tji[ty][tx * 4 + 0] = v.x; tji[ty][tx * 4 + 1] = v.y;
        tji[ty][tx * 4 + 2] = v.z; tji[ty][tx * 4 + 3] = v.w;
    }
    __syncthreads();
    const float4 mv = *(const float4*)&mod[(size_t)(bi + ty) * N + bj + tx * 4];
    float m4[4] = {mv.x, mv.y, mv.z, mv.w};
    int pkA = 0, pkAa = 0;
    #pragma unroll
    for (int k = 0; k < 4; ++k) {
        int jl = tx * 4 + k;
        float a = m4[k] + tji[jl][ty] - diag[bj + jl];  // exact small integer
        int ai = (int)a;
        cv[ty][jl] = (signed char)ai;
        int au = ai < 0 ? -ai : ai;
        pkA  |= (ai & 255) << (8 * k);
        pkAa |= (au & 255) << (8 * k);
    }
    *(int*)&A [(size_t)(bi + ty) * N + bj + tx * 4] = pkA;
    *(int*)&Aa[(size_t)(bi + ty) * N + bj + tx * 4] = pkAa;
    __syncthreads();
    int pkT = 0, pkTa = 0;
    #pragma unroll
    for (int k = 0; k < 4; ++k) {
        int il = tx * 4 + k;
        int v = cv[il][ty];                 // A[i-local=il][j-local=ty] -> AT[j][i]
        int va = v < 0 ? -v : v;
        pkT  |= (v  & 255) << (8 * k);
        pkTa |= (va & 255) << (8 * k);
    }
    *(int*)&AT [(size_t)(bj + ty) * N + bi + tx * 4] = pkT;
    *(int*)&ATa[(size_t)(bj + ty) * N + bi + tx * 4] = pkTa;
}

// ---------------- kernel 4: i8 GEMM-trace, 256x256 tile, 4-deep pipelined schedule -------
// acc[z] = sum_{i,k} (M.M)[i,k] * M[k,i], M = A (z=0) or |A| (z=1). Exact integer math.
//
// Schedule (T3+T4+T5 port of the 8-phase template):
//   4 LDS buffers (tile j uses buffer j&3), lookahead-3 prefetch via global_load_lds.
//   Per K-tile (BK=64): 2 phases x {8/4 ds_read_b128; 2 async loads(j+3); s_barrier;
//   lgkmcnt(0)+sched_barrier; setprio(1); 16 MFMA; setprio(0); [vmcnt(8) end of tile];
//   s_barrier}.  Steady-state vmcnt(8) = 12 in flight, wait only the oldest tile —
//   never drains to 0 in the main loop.  Raw s_barrier (no compiler vmcnt(0) drain).
//   Hazards: lookahead 3 < 4 buffers => staging never targets a buffer that is being
//   read this tile or the next two; the end-of-tile vmcnt+barrier makes buffer j+1
//   ready for tile j+1's phase-A ds_reads across all waves.
#define BK 64
#define NT (N / BK)      // 64 K-tiles
#define BUFSZ 32768      // A 16K + B 16K per buffer

__global__ __launch_bounds__(512, 2) void gemm_trace_i8(
        const signed char* __restrict__ Ag,
        const signed char* __restrict__ ATg,
        const signed char* __restrict__ Aag,
        const signed char* __restrict__ ATag,
        double* __restrict__ accs) {
    __shared__ __align__(16) signed char lds[4 * BUFSZ];   // 128 KiB
    __shared__ int red[8];
    const int z = blockIdx.z;
    const signed char* Asrc = z ? Aag  : Ag;    // M rows   (i-panel)
    const signed char* Bsrc = z ? ATag : ATg;   // MT rows  (k-panel), B[k][n] = MT[n][k]
    const int i0 = blockIdx.y * 256;
    const int k0 = blockIdx.x * 256;
    const int t = threadIdx.x;
    const int lane = t & 63;
    const int wave = t >> 6;        // 0..7
    const int wm = wave >> 2;       // 0..1 -> M offset wm*128
    const int wn = wave & 3;        // 0..3 -> N offset wn*64
    const int quad = lane >> 4;
    const int col  = lane & 15;

    // staging plan: A tile = 1024 chunks of 16B (256 rows x 4 slots); thread t owns
    // chunks t and t+512 of A, same of B.  LDS slot c holds global slot (c&3)^((r>>1)&3)
    // (involution; pre-swizzled global source, linear LDS dest — required by
    // global_load_lds).
    const int c1 = t;
    const int r1 = c1 >> 2;          // 0..127
    const int r2 = r1 + 128;
    const int s1 = (((c1 & 3) ^ ((r1 >> 1) & 3)) << 4);
    const int s2 = (((c1 & 3) ^ ((r2 >> 1) & 3)) << 4);
    const signed char* gA1 = Asrc + (size_t)(i0 + r1) * N + s1;
    const signed char* gA2 = Asrc + (size_t)(i0 + r2) * N + s2;
    const signed char* gB1 = Bsrc + (size_t)(k0 + r1) * N + s1;
    const signed char* gB2 = Bsrc + (size_t)(k0 + r2) * N + s2;
    const int ldsA1 = (wave * 64) * 16;           // wave-uniform LDS bases
    const int ldsA2 = 8192  + (wave * 64) * 16;
    const int ldsB1 = 16384 + (wave * 64) * 16;
    const int ldsB2 = 24576 + (wave * 64) * 16;
    const int fsw = ((quad ^ ((col >> 1) & 3)) << 4);  // fragment k-slot after swizzle

    int4v acc[8][4];
    #pragma unroll
    for (int a = 0; a < 8; ++a)
        #pragma unroll
        for (int b = 0; b < 4; ++b)
            acc[a][b] = (int4v){0, 0, 0, 0};

    // prologue: stage tiles 0,1,2 (12 loads in flight), wait tile 0 only
    for (int p = 0; p < 3; ++p) {
        const int pb = p * BUFSZ;
        const size_t go = (size_t)p * BK;
        async16(gA1 + go, lds + pb + ldsA1);
        async16(gA2 + go, lds + pb + ldsA2);
        async16(gB1 + go, lds + pb + ldsB1);
        async16(gB2 + go, lds + pb + ldsB2);
    }
    asm volatile("s_waitcnt vmcnt(8)" ::: "memory");
    __builtin_amdgcn_s_barrier();

    int4v bf[4];
    for (int j = 0; j < NT; ++j) {
        const int buf = (j & 3) * BUFSZ;
        const signed char* Ab = lds + buf;
        const signed char* Bb = lds + buf + 16384;
        const int pre = j + 3;
        const size_t go = (size_t)pre * BK;
        const int pb = (pre & 3) * BUFSZ;
        int4v af[4];
        // ---- phase A: m-half 0 ----
        #pragma unroll
        for (int tr = 0; tr < 4; ++tr)
            af[tr] = *(const int4v*)(Ab + ((wm * 128 + tr * 16 + col) << 6) + fsw);
        #pragma unroll
        for (int tc = 0; tc < 4; ++tc)
            bf[tc] = *(const int4v*)(Bb + ((wn * 64 + tc * 16 + col) << 6) + fsw);
        if (pre < NT) {
            async16(gA1 + go, lds + pb + ldsA1);
            async16(gA2 + go, lds + pb + ldsA2);
        }
        __builtin_amdgcn_s_barrier();
        asm volatile("s_waitcnt lgkmcnt(0)" ::: "memory");
        __builtin_amdgcn_sched_barrier(0);
        __builtin_amdgcn_s_setprio(1);
        #pragma unroll
        for (int tr = 0; tr < 4; ++tr)
            #pragma unroll
            for (int tc = 0; tc < 4; ++tc)
                acc[tr][tc] = __builtin_amdgcn_mfma_i32_16x16x64_i8(af[tr], bf[tc], acc[tr][tc], 0, 0, 0);
        __builtin_amdgcn_s_setprio(0);
        __builtin_amdgcn_s_barrier();
        // ---- phase B: m-half 1 (bf reused, k fixed per tile) ----
        #pragma unroll
        for (int tr = 0; tr < 4; ++tr)
            af[tr] = *(const int4v*)(Ab + ((wm * 128 + 64 + tr * 16 + col) << 6) + fsw);
        if (pre < NT) {
            async16(gB1 + go, lds + pb + ldsB1);
            async16(gB2 + go, lds + pb + ldsB2);
        }
        __builtin_amdgcn_s_barrier();
        asm volatile("s_waitcnt lgkmcnt(0)" ::: "memory");
        __builtin_amdgcn_sched_barrier(0);
        __builtin_amdgcn_s_setprio(1);
        #pragma unroll
        for (int tr = 0; tr < 4; ++tr)
            #pragma unroll
            for (int tc = 0; tc < 4; ++tc)
                acc[4 + tr][tc] = __builtin_amdgcn_mfma_i32_16x16x64_i8(af[tr], bf[tc], acc[4 + tr][tc], 0, 0, 0);
        __builtin_amdgcn_s_setprio(0);
        // end-of-tile counted wait: make buffer j+1 ready for next tile's phase-A reads
        if (j < NT - 3)       { asm volatile("s_waitcnt vmcnt(8)" ::: "memory"); }
        else if (j == NT - 3) { asm volatile("s_waitcnt vmcnt(4)" ::: "memory"); }
        else if (j == NT - 2) { asm volatile("s_waitcnt vmcnt(0)" ::: "memory"); }
        __builtin_amdgcn_s_barrier();
    }

    // trace epilogue: C/D layout col=lane&15, row=quad*4+reg (shape-determined).
    // multiplier M[k,i] = Asrc[kk*N + ib + r]: 4 consecutive bytes -> one int load.
    int part = 0;
    #pragma unroll
    for (int mr = 0; mr < 8; ++mr) {
        const int ib = i0 + wm * 128 + mr * 16 + quad * 4;
        #pragma unroll
        for (int tc = 0; tc < 4; ++tc) {
            const int kk = k0 + wn * 64 + tc * 16 + col;
            const int mv = *(const int*)&Asrc[(size_t)kk * N + ib];
            #pragma unroll
            for (int r = 0; r < 4; ++r)
                part += acc[mr][tc][r] * (int)(signed char)(mv >> (8 * r));
        }
    }
    #pragma unroll
    for (int off = 32; off > 0; off >>= 1)
        part += __shfl_down(part, off, 64);
    if (lane == 0) red[wave] = part;
    __syncthreads();
    if (t == 0) {
        int tot = 0;
        #pragma unroll
        for (int w = 0; w < 8; ++w) tot += red[w];
        atomicAdd(&accs[z], (double)tot);
    }
}

// ---------------- kernel 5: balance ----------------
__global__ void finalize_kernel(const double* __restrict__ accs, float* __restrict__ out) {
    out[NN] = (float)(0.5 * (1.0 + accs[0] / accs[1]));
}

extern "C" void kernel_launch(void* const* d_in, const int* in_sizes, int n_in,
                              void* d_out, int out_size, void* d_ws, size_t ws_size,
                              hipStream_t stream) {
    const float* ori = (const float*)d_in[0];
    const float* clp = (const float*)d_in[1];
    const float* u   = (const float*)d_in[2];
    float* out = (float*)d_out;
    char* ws = (char*)d_ws;
    signed char* A8   = (signed char*)ws;                    // 16 MiB
    signed char* AT8  = (signed char*)(ws + NN);             // 16 MiB
    signed char* Aa8  = (signed char*)(ws + 2 * NN);         // 16 MiB
    signed char* ATa8 = (signed char*)(ws + 3 * NN);         // 16 MiB
    float*       diag = (float*)(ws + 4 * NN);               // 16 KiB
    double*      accs = (double*)(ws + 4 * NN + 4096 * 4);   // 16 B

    mod_kernel<<<dim3((unsigned)(NN / 1024)), 256, 0, stream>>>(ori, clp, u, out);
    diag_kernel<<<dim3(16), 256, 0, stream>>>(out, diag, accs);
    build_A8<<<dim3(N / 32, N / 32), dim3(8, 32), 0, stream>>>(out, diag, A8, AT8, Aa8, ATa8);
    gemm_trace_i8<<<dim3(N / 256, N / 256, 2), 512, 0, stream>>>(A8, AT8, Aa8, ATa8, accs);
    finalize_kernel<<<1, 1, 0, stream>>>(accs, out);
}

// Round 3
// 365.643 us; speedup vs baseline: 1.1705x; 1.0342x over previous
//
#include <hip/hip_runtime.h>
#include <hip/hip_bf16.h>
#include <cstdint>
#include <cstddef>

#define N 4096
#define NN ((size_t)N * (size_t)N)

typedef int   int4v   __attribute__((ext_vector_type(4)));
typedef float float4v __attribute__((ext_vector_type(4)));

__device__ inline void async16(const void* g, void* lds) {
    __builtin_amdgcn_global_load_lds(
        (const __attribute__((address_space(1))) void*)g,
        (__attribute__((address_space(3))) void*)lds, 16, 0, 0);
}

// ---------------- kernel 1: straight-through relaxed Bernoulli flip ----------------
// Algebraic shortcut: hard = rint(sigmoid((logit(p)+logit(u))/tau)) == (p + u >= 1).
__global__ void mod_kernel(const float* __restrict__ ori,
                           const float* __restrict__ clp,
                           const float* __restrict__ u,
                           float* __restrict__ out) {
    size_t i = ((size_t)blockIdx.x * blockDim.x + threadIdx.x) * 4;
    const float4v p4 = *(const float4v*)(clp + i);
    const float4v u4 = *(const float4v*)(u + i);
    const float4v o4 = *(const float4v*)(ori + i);
    float4v r;
    #pragma unroll
    for (int c = 0; c < 4; ++c) {
        float hard = (p4[c] + u4[c] >= 1.0f) ? 1.0f : 0.0f;
        r[c] = fmaf(hard, -2.0f * o4[c], o4[c]);
    }
    *(float4v*)(out + i) = r;
}

// ---------------- kernel 2: diagonal extract + zero accumulators ----------------
__global__ void diag_kernel(const float* __restrict__ mod,
                            float* __restrict__ diag,
                            double* __restrict__ accs) {
    int j = blockIdx.x * blockDim.x + threadIdx.x;
    if (j < N) diag[j] = mod[(size_t)j * N + j];
    if (blockIdx.x == 0 && threadIdx.x < 2) accs[threadIdx.x] = 0.0;
}

// ---------------- kernel 3: A = mod + mod^T - diag(col) as i8: A, AT, |A|, |A|T ----------------
__global__ void build_A8(const float* __restrict__ mod,
                         const float* __restrict__ diag,
                         signed char* __restrict__ A,
                         signed char* __restrict__ AT,
                         signed char* __restrict__ Aa,
                         signed char* __restrict__ ATa) {
    __shared__ float tji[32][33];        // tji[j-local][i-local] = mod[j][i]
    __shared__ signed char cv[32][36];   // cv[i-local][j-local] = A value
    const int bi = blockIdx.x * 32;
    const int bj = blockIdx.y * 32;
    const int tx = threadIdx.x;   // 0..7  (groups of 4 cols)
    const int ty = threadIdx.y;   // 0..31 (rows)
    {
        const float4 v = *(const float4*)&mod[(size_t)(bj + ty) * N + bi + tx * 4];
        tji[ty][tx * 4 + 0] = v.x; tji[ty][tx * 4 + 1] = v.y;
        tji[ty][tx * 4 + 2] = v.z; tji[ty][tx * 4 + 3] = v.w;
    }
    __syncthreads();
    const float4 mv = *(const float4*)&mod[(size_t)(bi + ty) * N + bj + tx * 4];
    float m4[4] = {mv.x, mv.y, mv.z, mv.w};
    int pkA = 0, pkAa = 0;
    #pragma unroll
    for (int k = 0; k < 4; ++k) {
        int jl = tx * 4 + k;
        float a = m4[k] + tji[jl][ty] - diag[bj + jl];  // exact small integer
        int ai = (int)a;
        cv[ty][jl] = (signed char)ai;
        int au = ai < 0 ? -ai : ai;
        pkA  |= (ai & 255) << (8 * k);
        pkAa |= (au & 255) << (8 * k);
    }
    *(int*)&A [(size_t)(bi + ty) * N + bj + tx * 4] = pkA;
    *(int*)&Aa[(size_t)(bi + ty) * N + bj + tx * 4] = pkAa;
    __syncthreads();
    int pkT = 0, pkTa = 0;
    #pragma unroll
    for (int k = 0; k < 4; ++k) {
        int il = tx * 4 + k;
        int v = cv[il][ty];                 // A[i-local=il][j-local=ty] -> AT[j][i]
        int va = v < 0 ? -v : v;
        pkT  |= (v  & 255) << (8 * k);
        pkTa |= (va & 255) << (8 * k);
    }
    *(int*)&AT [(size_t)(bj + ty) * N + bi + tx * 4] = pkT;
    *(int*)&ATa[(size_t)(bj + ty) * N + bi + tx * 4] = pkTa;
}

// ---------------- kernel 4: i8 GEMM-trace, 256x256 tile, ONE barrier per K-tile -------
// acc[z] = sum_{i,k} (M.M)[i,k] * M[k,i], M = A (z=0) or |A| (z=1). Exact integer math.
//
// Schedule: 4 LDS buffers, lookahead-3 prefetch.  Per K-tile:
//   { 12 ds_read_b128 (af0, bf, af1); stage tile j+3 (4 gload_lds);
//     lgkmcnt(4) -> MFMA half0 (af1 reads complete under the MFMA cluster);
//     lgkmcnt(0) -> MFMA half1; vmcnt(8); s_barrier }.
// Hazards: staging targets buffer (j+3)&3 == (j-1)&3; every wave's reads of tile j-1
// completed (its own lgkmcnt(0)) before the end-of-tile-(j-1) barrier, so staging
// issued after that barrier cannot overwrite live data.  The end-of-tile vmcnt(8)
// (12 in flight -> oldest tile done) + barrier publishes tile j+1 to all waves.
// Counted waits only — vmcnt never drains to 0 in steady state.
#define BK 64
#define NT (N / BK)      // 64 K-tiles
#define BUFSZ 32768      // A 16K + B 16K per buffer

__global__ __launch_bounds__(512, 2) void gemm_trace_i8(
        const signed char* __restrict__ Ag,
        const signed char* __restrict__ ATg,
        const signed char* __restrict__ Aag,
        const signed char* __restrict__ ATag,
        double* __restrict__ accs) {
    __shared__ __align__(16) signed char lds[4 * BUFSZ];   // 128 KiB
    __shared__ int red[8];
    const int z = blockIdx.z;
    const signed char* Asrc = z ? Aag  : Ag;    // M rows   (i-panel)
    const signed char* Bsrc = z ? ATag : ATg;   // MT rows  (k-panel), B[k][n] = MT[n][k]
    const int i0 = blockIdx.y * 256;
    const int k0 = blockIdx.x * 256;
    const int t = threadIdx.x;
    const int lane = t & 63;
    const int wave = t >> 6;        // 0..7
    const int wm = wave >> 2;       // 0..1 -> M offset wm*128
    const int wn = wave & 3;        // 0..3 -> N offset wn*64
    const int quad = lane >> 4;
    const int col  = lane & 15;

    // staging plan: A tile = 1024 chunks of 16B (256 rows x 4 slots); thread t owns
    // chunks t and t+512.  LDS slot c holds global slot (c&3)^((r>>1)&3) (involution;
    // pre-swizzled global source, linear LDS dest — required by global_load_lds).
    const int c1 = t;
    const int r1 = c1 >> 2;          // 0..127
    const int r2 = r1 + 128;
    const int s1 = (((c1 & 3) ^ ((r1 >> 1) & 3)) << 4);
    const int s2 = (((c1 & 3) ^ ((r2 >> 1) & 3)) << 4);
    const signed char* gA1 = Asrc + (size_t)(i0 + r1) * N + s1;
    const signed char* gA2 = Asrc + (size_t)(i0 + r2) * N + s2;
    const signed char* gB1 = Bsrc + (size_t)(k0 + r1) * N + s1;
    const signed char* gB2 = Bsrc + (size_t)(k0 + r2) * N + s2;
    const int ldsA1 = (wave * 64) * 16;           // wave-uniform LDS bases
    const int ldsA2 = 8192  + (wave * 64) * 16;
    const int ldsB1 = 16384 + (wave * 64) * 16;
    const int ldsB2 = 24576 + (wave * 64) * 16;
    const int fsw = ((quad ^ ((col >> 1) & 3)) << 4);  // fragment k-slot after swizzle

    int4v acc[8][4];
    #pragma unroll
    for (int a = 0; a < 8; ++a)
        #pragma unroll
        for (int b = 0; b < 4; ++b)
            acc[a][b] = (int4v){0, 0, 0, 0};

    // prologue: stage tiles 0,1,2 (12 loads in flight), wait tile 0 only
    for (int p = 0; p < 3; ++p) {
        const int pb = p * BUFSZ;
        const size_t go = (size_t)p * BK;
        async16(gA1 + go, lds + pb + ldsA1);
        async16(gA2 + go, lds + pb + ldsA2);
        async16(gB1 + go, lds + pb + ldsB1);
        async16(gB2 + go, lds + pb + ldsB2);
    }
    asm volatile("s_waitcnt vmcnt(8)" ::: "memory");
    __builtin_amdgcn_s_barrier();
    __builtin_amdgcn_sched_barrier(0);

    for (int j = 0; j < NT; ++j) {
        const int buf = (j & 3) * BUFSZ;
        const signed char* Ab = lds + buf;
        const signed char* Bb = lds + buf + 16384;
        const int pre = j + 3;
        const size_t go = (size_t)pre * BK;
        const int pb = (pre & 3) * BUFSZ;
        int4v af0[4], af1[4], bf[4];
        // issue all 12 fragment reads up front (af0+bf oldest, af1 newest)
        #pragma unroll
        for (int tr = 0; tr < 4; ++tr)
            af0[tr] = *(const int4v*)(Ab + ((wm * 128 + tr * 16 + col) << 6) + fsw);
        #pragma unroll
        for (int tc = 0; tc < 4; ++tc)
            bf[tc] = *(const int4v*)(Bb + ((wn * 64 + tc * 16 + col) << 6) + fsw);
        #pragma unroll
        for (int tr = 0; tr < 4; ++tr)
            af1[tr] = *(const int4v*)(Ab + ((wm * 128 + 64 + tr * 16 + col) << 6) + fsw);
        // stage tile j+3 (buffer (j-1)&3 — safe: all waves past the end-of-tile-(j-1)
        // barrier, and their tile j-1 reads completed before that barrier)
        if (pre < NT) {
            async16(gA1 + go, lds + pb + ldsA1);
            async16(gA2 + go, lds + pb + ldsA2);
            async16(gB1 + go, lds + pb + ldsB1);
            async16(gB2 + go, lds + pb + ldsB2);
        }
        // half 0: wait af0+bf only (8 oldest of 12)
        asm volatile("s_waitcnt lgkmcnt(4)" ::: "memory");
        __builtin_amdgcn_sched_barrier(0);
        __builtin_amdgcn_s_setprio(1);
        #pragma unroll
        for (int tr = 0; tr < 4; ++tr)
            #pragma unroll
            for (int tc = 0; tc < 4; ++tc)
                acc[tr][tc] = __builtin_amdgcn_mfma_i32_16x16x64_i8(af0[tr], bf[tc], acc[tr][tc], 0, 0, 0);
        __builtin_amdgcn_s_setprio(0);
        // half 1: af1 completed under the half-0 MFMA cluster
        asm volatile("s_waitcnt lgkmcnt(0)" ::: "memory");
        __builtin_amdgcn_sched_barrier(0);
        __builtin_amdgcn_s_setprio(1);
        #pragma unroll
        for (int tr = 0; tr < 4; ++tr)
            #pragma unroll
            for (int tc = 0; tc < 4; ++tc)
                acc[4 + tr][tc] = __builtin_amdgcn_mfma_i32_16x16x64_i8(af1[tr], bf[tc], acc[4 + tr][tc], 0, 0, 0);
        __builtin_amdgcn_s_setprio(0);
        // end-of-tile counted wait: tile j+1's staging landed; single barrier per tile
        if (j < NT - 3)       { asm volatile("s_waitcnt vmcnt(8)" ::: "memory"); }
        else if (j == NT - 3) { asm volatile("s_waitcnt vmcnt(4)" ::: "memory"); }
        else if (j == NT - 2) { asm volatile("s_waitcnt vmcnt(0)" ::: "memory"); }
        __builtin_amdgcn_s_barrier();
        __builtin_amdgcn_sched_barrier(0);
    }

    // trace epilogue: C/D layout col=lane&15, row=quad*4+reg (shape-determined).
    // multiplier M[k,i] = Asrc[kk*N + ib + r]: 4 consecutive bytes -> one int load.
    int part = 0;
    #pragma unroll
    for (int mr = 0; mr < 8; ++mr) {
        const int ib = i0 + wm * 128 + mr * 16 + quad * 4;
        #pragma unroll
        for (int tc = 0; tc < 4; ++tc) {
            const int kk = k0 + wn * 64 + tc * 16 + col;
            const int mv = *(const int*)&Asrc[(size_t)kk * N + ib];
            #pragma unroll
            for (int r = 0; r < 4; ++r)
                part += acc[mr][tc][r] * (int)(signed char)(mv >> (8 * r));
        }
    }
    #pragma unroll
    for (int off = 32; off > 0; off >>= 1)
        part += __shfl_down(part, off, 64);
    if (lane == 0) red[wave] = part;
    __syncthreads();
    if (t == 0) {
        int tot = 0;
        #pragma unroll
        for (int w = 0; w < 8; ++w) tot += red[w];
        atomicAdd(&accs[z], (double)tot);
    }
}

// ---------------- kernel 5: balance ----------------
__global__ void finalize_kernel(const double* __restrict__ accs, float* __restrict__ out) {
    out[NN] = (float)(0.5 * (1.0 + accs[0] / accs[1]));
}

extern "C" void kernel_launch(void* const* d_in, const int* in_sizes, int n_in,
                              void* d_out, int out_size, void* d_ws, size_t ws_size,
                              hipStream_t stream) {
    const float* ori = (const float*)d_in[0];
    const float* clp = (const float*)d_in[1];
    const float* u   = (const float*)d_in[2];
    float* out = (float*)d_out;
    char* ws = (char*)d_ws;
    signed char* A8   = (signed char*)ws;                    // 16 MiB
    signed char* AT8  = (signed char*)(ws + NN);             // 16 MiB
    signed char* Aa8  = (signed char*)(ws + 2 * NN);         // 16 MiB
    signed char* ATa8 = (signed char*)(ws + 3 * NN);         // 16 MiB
    float*       diag = (float*)(ws + 4 * NN);               // 16 KiB
    double*      accs = (double*)(ws + 4 * NN + 4096 * 4);   // 16 B

    mod_kernel<<<dim3((unsigned)(NN / 1024)), 256, 0, stream>>>(ori, clp, u, out);
    diag_kernel<<<dim3(16), 256, 0, stream>>>(out, diag, accs);
    build_A8<<<dim3(N / 32, N / 32), dim3(8, 32), 0, stream>>>(out, diag, A8, AT8, Aa8, ATa8);
    gemm_trace_i8<<<dim3(N / 256, N / 256, 2), 512, 0, stream>>>(A8, AT8, Aa8, ATa8, accs);
    finalize_kernel<<<1, 1, 0, stream>>>(accs, out);
}